// Round 12
// baseline (50.051 us; speedup 1.0000x reference)
//
#include <hip/hip_runtime.h>

#define N_PED  8192
#define HID    128
#define NN     36
#define IPB    8             // i-rows per block
#define SLICES 64            // j-slices per block (one per 8-thread group)
#define BLOCK  512           // IPB * SLICES
#define JS     128           // j's per thread (8192/64); counts/bin <= 127 cap
#define NB     1024          // 8192 / IPB

typedef unsigned long long u64;
typedef unsigned u32;

// Carry-save full adder over 64-bit bit-planes (alias-safe).
#define CSA(s, r, a, b, c) do { u64 _a=(a), _b=(b), _c=(c); u64 _t=_a^_b; \
    (r) = (_a & _b) | (_t & _c); (s) = _t ^ _c; } while (0)

// bin(pair) -> one-hot 64-bit (bit 0..35 valid, bit 63 = trash for
// out-of-range / NaN / inf; bit-sliced planes are bitwise-independent,
// so trash-bit overflow cannot contaminate real bins).
__device__ __forceinline__ u64 onehot(float px, float py, float xi4, float yi4) {
    float dx = px - xi4;                  // xj - xi + 4; valid range [1,7)
    float dy = py - yi4;
    u32 u1 = (u32)((int)dx) - 1u;         // NaN/inf/neg -> huge unsigned
    u32 u2 = (u32)((int)dy) - 1u;
    u32 mx = u1 > u2 ? u1 : u2;
    u32 bin = u1 * 6u + u2;
    bin = (mx < 6u) ? bin : 63u;
    return 1ull << bin;
}

// Add 8 one-hot items into 7 bit-planes (weights 1..64) via a static CSA
// tree: 7 CSA + 3 half-adds. Capacity 127 per bin per thread; only the
// physically impossible all-128-pairs-in-one-valid-bin case would overflow.
__device__ __forceinline__ void add8(
    u64 x0, u64 x1, u64 x2, u64 x3, u64 x4, u64 x5, u64 x6, u64 x7,
    u64& R1, u64& R2, u64& R4, u64& R8, u64& R16, u64& R32, u64& R64)
{
    u64 s0,c0,s1,c1,s2,c2,c3,s4,c4,c5,c6,c7,c8,c9;
    CSA(s0, c0, x0, x1, x2);
    CSA(s1, c1, x3, x4, x5);
    CSA(s2, c2, x6, x7, s0);
    CSA(R1, c3, s1, s2, R1);          // weight-1 residue
    CSA(s4, c4, c0, c1, c2);          // weight-2 items
    CSA(R2, c5, s4, c3, R2);
    CSA(R4, c6, c4, c5, R4);          // weight-4
    c7 = R8  & c6;  R8  ^= c6;        // weight-8  half-add
    c8 = R16 & c7;  R16 ^= c7;        // weight-16
    c9 = R32 & c8;  R32 ^= c8;        // weight-32
    R64 |= c9;                        // weight-64 (saturating top)
}

__global__ __launch_bounds__(BLOCK, 4) void pool_kernel(
    const float* __restrict__ obs2_g,   // [8192][2]
    const float* __restrict__ Wg,       // [128][36] row-major
    const float* __restrict__ bias,     // [128]
    float* __restrict__ out)            // [8192][128]
{
    __shared__ u32  s_h[9 * BLOCK];                // 18,432 B byte-packed hist
    __shared__ float s_rgrid[IPB][NN];             //  1,152 B
    __shared__ u32  s_wsel[IPB];                   //     32 B
    // ~19.6 KB LDS; no zeroing needed (flush overwrites every word)

    const int tid = threadIdx.x;
    const int bid = blockIdx.x;

    const int il    = tid & (IPB - 1);
    const int slice = tid >> 3;                    // 0..63
    const int i     = bid * IPB + il;

    const float2 pi = ((const float2*)obs2_g)[i];
    const float  xi4 = pi.x - 4.0f;
    const float  yi4 = pi.y - 4.0f;

    // self-pair bin via IDENTICAL arithmetic (handles fl(xi - fl(xi-4)) != 4)
    if (tid < IPB) {
        float dx = pi.x - xi4;
        float dy = pi.y - yi4;
        u32 u1 = (u32)((int)dx) - 1u;
        u32 u2 = (u32)((int)dy) - 1u;
        bool ok = (u1 < 6u) & (u2 < 6u);           // false iff NaN/inf row
        s_wsel[il] = ok ? (u1 * 6u + u2) : 255u;
    }

    // ---- Phase 1: pairwise histogram, all in registers (zero DS in loop)
    u64 R1=0, R2=0, R4=0, R8=0, R16=0, R32=0, R64=0;

    #define GRP8(r0, r1, r2, r3)                                         \
        add8(onehot(r0.x, r0.y, xi4, yi4), onehot(r0.z, r0.w, xi4, yi4), \
             onehot(r1.x, r1.y, xi4, yi4), onehot(r1.z, r1.w, xi4, yi4), \
             onehot(r2.x, r2.y, xi4, yi4), onehot(r2.z, r2.w, xi4, yi4), \
             onehot(r3.x, r3.y, xi4, yi4), onehot(r3.z, r3.w, xi4, yi4), \
             R1, R2, R4, R8, R16, R32, R64)

    {
        const float4* jp = (const float4*)obs2_g + slice * (JS / 2);  // 64 f4
        float4 a0 = jp[0], a1 = jp[1], a2 = jp[2], a3 = jp[3];
        float4 b0 = jp[4], b1 = jp[5], b2 = jp[6], b3 = jp[7];
        jp += 8;
        #pragma unroll 1
        for (int it = 0; it < 7; ++it) {          // 7 x 16 + 16 = 128 pairs
            GRP8(a0, a1, a2, a3);
            a0 = jp[0]; a1 = jp[1]; a2 = jp[2]; a3 = jp[3];
            GRP8(b0, b1, b2, b3);
            b0 = jp[4]; b1 = jp[5]; b2 = jp[6]; b3 = jp[7];
            jp += 8;
        }
        GRP8(a0, a1, a2, a3);
        GRP8(b0, b1, b2, b3);
    }
    #undef GRP8

    // ---- Flush: planes -> byte-packed counts, written (not added) to LDS.
    // spread: nibble n (bits b0..b0+3) -> bytes via (n*0x00204081)&0x01010101
    // (k+7j sums are all distinct for k,j in 0..3 -> carry-free), then <<L.
    {
        const u32 lo[7] = { (u32)R1,  (u32)R2,  (u32)R4,  (u32)R8,
                            (u32)R16, (u32)R32, (u32)R64 };
        const u32 hi[7] = { (u32)(R1>>32),  (u32)(R2>>32),  (u32)(R4>>32),
                            (u32)(R8>>32),  (u32)(R16>>32), (u32)(R32>>32),
                            (u32)(R64>>32) };
        #pragma unroll
        for (int w = 0; w < 9; ++w) {
            u32 acc = 0;
            #pragma unroll
            for (int L = 0; L < 7; ++L) {
                u32 nib = (w < 8) ? ((lo[L] >> (4 * w)) & 0xFu)
                                  : (hi[L] & 0xFu);
                acc += ((nib * 0x00204081u) & 0x01010101u) << L;
            }
            s_h[w * BLOCK + tid] = acc;            // bank = tid%32, no conflict
        }
    }
    __syncthreads();

    // ---- Phase 2: byte-wise reduce over 64 slices (72 tasks)
    if (tid < IPB * 9) {                           // 72
        const int ril = tid & (IPB - 1);
        const int w   = tid >> 3;                  // 0..8
        u32 lo = 0u, hi = 0u;                      // 2x u16 lanes each (max 8128)
        #pragma unroll 8
        for (int sl = 0; sl < SLICES; ++sl) {
            u32 a = s_h[(w << 9) + sl * IPB + ril];
            lo += a & 0x00FF00FFu;
            hi += (a >> 8) & 0x00FF00FFu;
        }
        u32 s0 = lo & 0xFFFFu;
        u32 s1 = hi & 0xFFFFu;
        u32 s2 = lo >> 16;
        u32 s3 = hi >> 16;
        const u32 sel  = s_wsel[ril];
        const u32 base = (u32)(w * 4);
        s0 -= (sel == base + 0u);
        s1 -= (sel == base + 1u);
        s2 -= (sel == base + 2u);
        s3 -= (sel == base + 3u);
        s_rgrid[ril][base + 0] = (float)s0;
        s_rgrid[ril][base + 1] = (float)s1;
        s_rgrid[ril][base + 2] = (float)s2;
        s_rgrid[ril][base + 3] = (float)s3;
    }
    __syncthreads();

    // ---- Phase 3: fused GEMM  out[i][h] = sum_k grid[i][k]*W[h][k] + b[h]
    const int h  = tid & (HID - 1);                // 0..127
    const int r0 = tid >> 7;                       // 0..3 (wave-pair uniform)
    const float4* W4 = (const float4*)Wg;          // [128][9] float4

    const float bh = bias[h];
    float acc0 = bh, acc1 = bh;

    #pragma unroll
    for (int k4 = 0; k4 < 9; ++k4) {
        float4 w4 = W4[h * 9 + k4];
        float4 g0 = *(const float4*)&s_rgrid[r0    ][k4 * 4];
        float4 g1 = *(const float4*)&s_rgrid[r0 + 4][k4 * 4];
        acc0 += g0.x * w4.x + g0.y * w4.y + g0.z * w4.z + g0.w * w4.w;
        acc1 += g1.x * w4.x + g1.y * w4.y + g1.z * w4.z + g1.w * w4.w;
    }

    const int obase = bid * IPB;
    out[(obase + r0    ) * HID + h] = acc0;
    out[(obase + r0 + 4) * HID + h] = acc1;
}

extern "C" void kernel_launch(void* const* d_in, const int* in_sizes, int n_in,
                              void* d_out, int out_size, void* d_ws, size_t ws_size,
                              hipStream_t stream) {
    // inputs: 0=hidden_state (unused), 1=obs1 (unused), 2=obs2, 3=W, 4=b
    const float* obs2 = (const float*)d_in[2];
    const float* W    = (const float*)d_in[3];
    const float* b    = (const float*)d_in[4];
    float* out        = (float*)d_out;
    (void)in_sizes; (void)n_in; (void)out_size; (void)d_ws; (void)ws_size;

    hipLaunchKernelGGL(pool_kernel, dim3(NB), dim3(BLOCK), 0, stream,
                       obs2, W, b, out);
}

// Round 13
// 49.962 us; speedup vs baseline: 1.0018x; 1.0018x over previous
//
#include <hip/hip_runtime.h>

#define N_PED  8192
#define HID    128
#define NN     36
#define IPB    8             // i-rows per block
#define SLICES 64            // j-slices per block (one per 8-thread group)
#define BLOCK  512           // IPB * SLICES
#define JS     128           // j's per thread (8192/64); counts/bin <= 127+sat
#define NB     1024          // 8192 / IPB

typedef unsigned long long u64;
typedef unsigned u32;

// Carry-save full adder over 64-bit bit-planes (pure bitwise; compiler
// lowers u64 to exactly 2x 32-bit VALU per op — no selects, no branches).
#define CSA(s, r, a, b, c) do { u64 _a=(a), _b=(b), _c=(c); u64 _t=_a^_b; \
    (r) = (_a & _b) | (_t & _c); (s) = _t ^ _c; } while (0)

// One pair -> one-hot u64, asm-pinned: EXACTLY 11 VALU.
//   u1=trunc(px-xi4)-1, u2=trunc(py-yi4)-1 (NaN/inf/neg -> huge unsigned)
//   bin = valid ? u1*6+u2 : 63 (trash bit; planes are bitwise-independent)
//   onehot = 1ull << bin   (v_lshlrev_b64: D = S1 << S0, src1=1 inline)
__device__ __forceinline__ u64 onehot_asm(float px, float py,
                                          float xi4, float yi4) {
    u64 oh; u32 t0, t1, t2;
    asm("v_sub_f32 %[t0], %[px], %[xi4]\n\t"
        "v_sub_f32 %[t1], %[py], %[yi4]\n\t"
        "v_cvt_i32_f32 %[t0], %[t0]\n\t"
        "v_cvt_i32_f32 %[t1], %[t1]\n\t"
        "v_add_u32 %[t0], -1, %[t0]\n\t"
        "v_add_u32 %[t1], -1, %[t1]\n\t"
        "v_max_u32 %[t2], %[t0], %[t1]\n\t"
        "v_mad_u32_u24 %[t0], %[t0], 6, %[t1]\n\t"
        "v_cmp_gt_u32 vcc, 6, %[t2]\n\t"
        "v_cndmask_b32 %[t0], 63, %[t0], vcc\n\t"
        "v_lshlrev_b64 %[oh], %[t0], 1"
        : [oh]"=v"(oh), [t0]"=&v"(t0), [t1]"=&v"(t1), [t2]"=&v"(t2)
        : [px]"v"(px), [py]"v"(py), [xi4]"v"(xi4), [yi4]"v"(yi4)
        : "vcc");
    return oh;
}

// Add 8 one-hot items into 7 bit-planes (weights 1..64): 7 CSA + 3 half-adds
// + saturating top. 42 u64 ops = 84 VALU per 8 pairs. Capacity 127/bin +
// saturation; trash bit 63 saturates harmlessly (bitwise independence).
__device__ __forceinline__ void add8(
    u64 x0, u64 x1, u64 x2, u64 x3, u64 x4, u64 x5, u64 x6, u64 x7,
    u64& R1, u64& R2, u64& R4, u64& R8, u64& R16, u64& R32, u64& R64)
{
    u64 s0,c0,s1,c1,s2,c2,c3,s4,c4,c5,c6,c7,c8,c9;
    CSA(s0, c0, x0, x1, x2);
    CSA(s1, c1, x3, x4, x5);
    CSA(s2, c2, x6, x7, s0);
    CSA(R1, c3, s1, s2, R1);          // weight-1 residue
    CSA(s4, c4, c0, c1, c2);          // weight-2 items
    CSA(R2, c5, s4, c3, R2);
    CSA(R4, c6, c4, c5, R4);          // weight-4
    c7 = R8  & c6;  R8  ^= c6;        // weight-8  half-add
    c8 = R16 & c7;  R16 ^= c7;        // weight-16
    c9 = R32 & c8;  R32 ^= c8;        // weight-32
    R64 |= c9;                        // weight-64 (saturating top)
}

__global__ __launch_bounds__(BLOCK, 6) void pool_kernel(
    const float* __restrict__ obs2_g,   // [8192][2]
    const float* __restrict__ Wg,       // [128][36] row-major
    const float* __restrict__ bias,     // [128]
    float* __restrict__ out)            // [8192][128]
{
    __shared__ u32   s_h[9 * BLOCK];               // 18,432 B byte-packed hist
    __shared__ float s_rgrid[IPB][NN];             //  1,152 B
    __shared__ u32   s_wsel[IPB];                  //     32 B
    // ~19.6 KB LDS -> 3 blocks/CU via launch_bounds(512,6); VGPR cap 85.

    const int tid = threadIdx.x;
    const int bid = blockIdx.x;

    const int il    = tid & (IPB - 1);
    const int slice = tid >> 3;                    // 0..63
    const int i     = bid * IPB + il;

    const float2 pi = ((const float2*)obs2_g)[i];
    const float  xi4 = pi.x - 4.0f;
    const float  yi4 = pi.y - 4.0f;

    // self-pair bin via IDENTICAL arithmetic (handles fl(xi - fl(xi-4)) != 4)
    if (tid < IPB) {
        float dx = pi.x - xi4;
        float dy = pi.y - yi4;
        u32 u1 = (u32)((int)dx) - 1u;
        u32 u2 = (u32)((int)dy) - 1u;
        bool ok = (u1 < 6u) & (u2 < 6u);           // false iff NaN/inf row
        s_wsel[il] = ok ? (u1 * 6u + u2) : 255u;
    }

    // ---- Phase 1: pairwise histogram, all in registers (zero DS in loop)
    u64 R1=0, R2=0, R4=0, R8=0, R16=0, R32=0, R64=0;

    #define GRP8(r0, r1, r2, r3)                                             \
        add8(onehot_asm(r0.x, r0.y, xi4, yi4), onehot_asm(r0.z, r0.w, xi4, yi4), \
             onehot_asm(r1.x, r1.y, xi4, yi4), onehot_asm(r1.z, r1.w, xi4, yi4), \
             onehot_asm(r2.x, r2.y, xi4, yi4), onehot_asm(r2.z, r2.w, xi4, yi4), \
             onehot_asm(r3.x, r3.y, xi4, yi4), onehot_asm(r3.z, r3.w, xi4, yi4), \
             R1, R2, R4, R8, R16, R32, R64)

    {
        const float4* jp = (const float4*)obs2_g + slice * (JS / 2);  // 64 f4
        float4 a0 = jp[0], a1 = jp[1], a2 = jp[2], a3 = jp[3];
        float4 b0 = jp[4], b1 = jp[5], b2 = jp[6], b3 = jp[7];
        jp += 8;
        #pragma unroll 1
        for (int it = 0; it < 7; ++it) {          // 7 x 16 + 16 = 128 pairs
            GRP8(a0, a1, a2, a3);
            a0 = jp[0]; a1 = jp[1]; a2 = jp[2]; a3 = jp[3];
            GRP8(b0, b1, b2, b3);
            b0 = jp[4]; b1 = jp[5]; b2 = jp[6]; b3 = jp[7];
            jp += 8;
        }
        GRP8(a0, a1, a2, a3);
        GRP8(b0, b1, b2, b3);
    }
    #undef GRP8

    // ---- Flush: planes -> byte-packed counts, written (not added) to LDS.
    // nibble n -> 4 bytes via (n*0x00204081)&0x01010101 (carry-free), <<L.
    {
        const u32 lo[7] = { (u32)R1,  (u32)R2,  (u32)R4,  (u32)R8,
                            (u32)R16, (u32)R32, (u32)R64 };
        const u32 hi[7] = { (u32)(R1>>32),  (u32)(R2>>32),  (u32)(R4>>32),
                            (u32)(R8>>32),  (u32)(R16>>32), (u32)(R32>>32),
                            (u32)(R64>>32) };
        #pragma unroll
        for (int w = 0; w < 9; ++w) {
            u32 acc = 0;
            #pragma unroll
            for (int L = 0; L < 7; ++L) {
                u32 nib = (w < 8) ? ((lo[L] >> (4 * w)) & 0xFu)
                                  : (hi[L] & 0xFu);
                acc += ((nib * 0x00204081u) & 0x01010101u) << L;
            }
            s_h[w * BLOCK + tid] = acc;            // bank = tid%32, no conflict
        }
    }
    __syncthreads();

    // ---- Phase 2: byte-wise reduce over 64 slices (72 tasks)
    if (tid < IPB * 9) {                           // 72
        const int ril = tid & (IPB - 1);
        const int w   = tid >> 3;                  // 0..8
        u32 lo = 0u, hi = 0u;                      // 2x u16 lanes each
        #pragma unroll 8
        for (int sl = 0; sl < SLICES; ++sl) {
            u32 a = s_h[(w << 9) + sl * IPB + ril];
            lo += a & 0x00FF00FFu;
            hi += (a >> 8) & 0x00FF00FFu;
        }
        u32 s0 = lo & 0xFFFFu;
        u32 s1 = hi & 0xFFFFu;
        u32 s2 = lo >> 16;
        u32 s3 = hi >> 16;
        const u32 sel  = s_wsel[ril];
        const u32 base = (u32)(w * 4);
        s0 -= (sel == base + 0u);
        s1 -= (sel == base + 1u);
        s2 -= (sel == base + 2u);
        s3 -= (sel == base + 3u);
        s_rgrid[ril][base + 0] = (float)s0;
        s_rgrid[ril][base + 1] = (float)s1;
        s_rgrid[ril][base + 2] = (float)s2;
        s_rgrid[ril][base + 3] = (float)s3;
    }
    __syncthreads();

    // ---- Phase 3: fused GEMM  out[i][h] = sum_k grid[i][k]*W[h][k] + b[h]
    const int h  = tid & (HID - 1);                // 0..127
    const int r0 = tid >> 7;                       // 0..3 (wave-pair uniform)
    const float4* W4 = (const float4*)Wg;          // [128][9] float4

    const float bh = bias[h];
    float acc0 = bh, acc1 = bh;

    #pragma unroll
    for (int k4 = 0; k4 < 9; ++k4) {
        float4 w4 = W4[h * 9 + k4];
        float4 g0 = *(const float4*)&s_rgrid[r0    ][k4 * 4];
        float4 g1 = *(const float4*)&s_rgrid[r0 + 4][k4 * 4];
        acc0 += g0.x * w4.x + g0.y * w4.y + g0.z * w4.z + g0.w * w4.w;
        acc1 += g1.x * w4.x + g1.y * w4.y + g1.z * w4.z + g1.w * w4.w;
    }

    const int obase = bid * IPB;
    out[(obase + r0    ) * HID + h] = acc0;
    out[(obase + r0 + 4) * HID + h] = acc1;
}

extern "C" void kernel_launch(void* const* d_in, const int* in_sizes, int n_in,
                              void* d_out, int out_size, void* d_ws, size_t ws_size,
                              hipStream_t stream) {
    // inputs: 0=hidden_state (unused), 1=obs1 (unused), 2=obs2, 3=W, 4=b
    const float* obs2 = (const float*)d_in[2];
    const float* W    = (const float*)d_in[3];
    const float* b    = (const float*)d_in[4];
    float* out        = (float*)d_out;
    (void)in_sizes; (void)n_in; (void)out_size; (void)d_ws; (void)ws_size;

    hipLaunchKernelGGL(pool_kernel, dim3(NB), dim3(BLOCK), 0, stream,
                       obs2, W, b, out);
}

// Round 14
// 39.300 us; speedup vs baseline: 1.2736x; 1.2713x over previous
//
#include <hip/hip_runtime.h>

#define N_PED  8192
#define HID    128
#define NN     36
#define IPB    8             // i-rows per block
#define SLICES 64            // j-slices per block (one per 8-thread group)
#define BLOCK  512           // IPB * SLICES
#define JS     128           // j's per thread
#define NB     1024          // 8192 / IPB
#define DSWAVES 5            // waves 0..4 -> ds_add path; 5..7 -> CSA path

typedef unsigned long long u64;
typedef unsigned u32;

// ---------- DS path (R7, measured 21 cyc/pair on DS pipe, 15 VALU) ----------
__device__ __forceinline__ void pair_asm(float px, float py, float xi4, float yi4,
                                         unsigned vone, unsigned vbase) {
    unsigned t0, t1, t2;
    asm volatile(
        "v_sub_f32 %0, %3, %5\n\t"
        "v_sub_f32 %1, %4, %6\n\t"
        "v_cvt_i32_f32 %0, %0\n\t"
        "v_cvt_i32_f32 %1, %1\n\t"
        "v_add_u32 %0, -1, %0\n\t"
        "v_add_u32 %1, -1, %1\n\t"
        "v_max_u32 %2, %0, %1\n\t"
        "v_mad_u32_u24 %0, %0, 6, %1\n\t"
        "v_cmp_gt_u32 vcc, 6, %2\n\t"
        "v_lshrrev_b32 %2, 2, %0\n\t"
        "v_cndmask_b32 %2, 9, %2, vcc\n\t"
        "v_lshlrev_b32 %1, 3, %0\n\t"
        "v_lshlrev_b32 %1, %1, %7\n\t"
        "v_lshl_add_u32 %2, %2, 11, %8\n\t"
        "ds_add_u32 %2, %1\n\t"
        : "=&v"(t0), "=&v"(t1), "=&v"(t2)
        : "v"(px), "v"(py), "v"(xi4), "v"(yi4), "v"(vone), "v"(vbase)
        : "vcc");
}

// ---------- CSA path (R12, VALU-only, zero DS in loop) ----------
#define CSA(s, r, a, b, c) do { u64 _a=(a), _b=(b), _c=(c); u64 _t=_a^_b; \
    (r) = (_a & _b) | (_t & _c); (s) = _t ^ _c; } while (0)

__device__ __forceinline__ u64 onehot_asm(float px, float py,
                                          float xi4, float yi4) {
    u64 oh; u32 t0, t1, t2;
    asm("v_sub_f32 %[t0], %[px], %[xi4]\n\t"
        "v_sub_f32 %[t1], %[py], %[yi4]\n\t"
        "v_cvt_i32_f32 %[t0], %[t0]\n\t"
        "v_cvt_i32_f32 %[t1], %[t1]\n\t"
        "v_add_u32 %[t0], -1, %[t0]\n\t"
        "v_add_u32 %[t1], -1, %[t1]\n\t"
        "v_max_u32 %[t2], %[t0], %[t1]\n\t"
        "v_mad_u32_u24 %[t0], %[t0], 6, %[t1]\n\t"
        "v_cmp_gt_u32 vcc, 6, %[t2]\n\t"
        "v_cndmask_b32 %[t0], 63, %[t0], vcc\n\t"
        "v_lshlrev_b64 %[oh], %[t0], 1"
        : [oh]"=v"(oh), [t0]"=&v"(t0), [t1]"=&v"(t1), [t2]"=&v"(t2)
        : [px]"v"(px), [py]"v"(py), [xi4]"v"(xi4), [yi4]"v"(yi4)
        : "vcc");
    return oh;
}

__device__ __forceinline__ void add8(
    u64 x0, u64 x1, u64 x2, u64 x3, u64 x4, u64 x5, u64 x6, u64 x7,
    u64& R1, u64& R2, u64& R4, u64& R8, u64& R16, u64& R32, u64& R64)
{
    u64 s0,c0,s1,c1,s2,c2,c3,s4,c4,c5,c6,c7,c8,c9;
    CSA(s0, c0, x0, x1, x2);
    CSA(s1, c1, x3, x4, x5);
    CSA(s2, c2, x6, x7, s0);
    CSA(R1, c3, s1, s2, R1);
    CSA(s4, c4, c0, c1, c2);
    CSA(R2, c5, s4, c3, R2);
    CSA(R4, c6, c4, c5, R4);
    c7 = R8  & c6;  R8  ^= c6;
    c8 = R16 & c7;  R16 ^= c7;
    c9 = R32 & c8;  R32 ^= c8;
    R64 |= c9;
}

__global__ __launch_bounds__(BLOCK, 4) void pool_kernel(
    const float* __restrict__ obs2_g,   // [8192][2]
    const float* __restrict__ Wg,       // [128][36] row-major
    const float* __restrict__ bias,     // [128]
    float* __restrict__ out)            // [8192][128]
{
    __shared__ u32   s_h[10 * BLOCK];              // 20,480 B (word 9 = DS trash)
    __shared__ float s_rgrid[IPB][NN];             //  1,152 B
    __shared__ u32   s_wsel[IPB];                  //     32 B

    const int tid = threadIdx.x;
    const int bid = blockIdx.x;

    const int il    = tid & (IPB - 1);
    const int slice = tid >> 3;                    // 0..63
    const int i     = bid * IPB + il;

    const float2 pi = ((const float2*)obs2_g)[i];
    const float  xi4 = pi.x - 4.0f;
    const float  yi4 = pi.y - 4.0f;

    // self-pair bin via IDENTICAL arithmetic (handles fl(xi - fl(xi-4)) != 4)
    if (tid < IPB) {
        float dx = pi.x - xi4;
        float dy = pi.y - yi4;
        u32 u1 = (u32)((int)dx) - 1u;
        u32 u2 = (u32)((int)dy) - 1u;
        bool ok = (u1 < 6u) & (u2 < 6u);
        s_wsel[il] = ok ? (u1 * 6u + u2) : 255u;
    }

    // zero own columns (thread-private -> no barrier needed before use)
    #pragma unroll
    for (int k = 0; k < 10; ++k)
        s_h[tid + k * BLOCK] = 0u;

    const float4* jp = (const float4*)obs2_g + slice * (JS / 2);  // 64 float4
    const int wave = tid >> 6;                     // 0..7

    if (wave < DSWAVES) {
        // ---------------- DS path: ds_add scatter (R7) ----------------
        const unsigned vone  = 1u;
        const unsigned vbase = (unsigned)(uintptr_t)&s_h[tid];

        #define PAIR8(r0, r1, r2, r3) do {                          \
            pair_asm(r0.x, r0.y, xi4, yi4, vone, vbase);            \
            pair_asm(r0.z, r0.w, xi4, yi4, vone, vbase);            \
            pair_asm(r1.x, r1.y, xi4, yi4, vone, vbase);            \
            pair_asm(r1.z, r1.w, xi4, yi4, vone, vbase);            \
            pair_asm(r2.x, r2.y, xi4, yi4, vone, vbase);            \
            pair_asm(r2.z, r2.w, xi4, yi4, vone, vbase);            \
            pair_asm(r3.x, r3.y, xi4, yi4, vone, vbase);            \
            pair_asm(r3.z, r3.w, xi4, yi4, vone, vbase);            \
        } while (0)

        float4 a0 = jp[0], a1 = jp[1], a2 = jp[2], a3 = jp[3];
        float4 b0 = jp[4], b1 = jp[5], b2 = jp[6], b3 = jp[7];
        jp += 8;
        #pragma unroll 1
        for (int it = 0; it < 7; ++it) {           // 7 x 16 + 16 = 128 pairs
            PAIR8(a0, a1, a2, a3);
            a0 = jp[0]; a1 = jp[1]; a2 = jp[2]; a3 = jp[3];
            PAIR8(b0, b1, b2, b3);
            b0 = jp[4]; b1 = jp[5]; b2 = jp[6]; b3 = jp[7];
            jp += 8;
        }
        PAIR8(a0, a1, a2, a3);
        PAIR8(b0, b1, b2, b3);
        #undef PAIR8

        // asm DS ops invisible to compiler waitcnt: drain before barrier
        asm volatile("s_waitcnt lgkmcnt(0)" ::: "memory");
    } else {
        // ---------------- CSA path: register bit-planes (R12) ----------------
        u64 R1=0, R2=0, R4=0, R8=0, R16=0, R32=0, R64=0;

        #define GRP8(r0, r1, r2, r3)                                             \
            add8(onehot_asm(r0.x, r0.y, xi4, yi4), onehot_asm(r0.z, r0.w, xi4, yi4), \
                 onehot_asm(r1.x, r1.y, xi4, yi4), onehot_asm(r1.z, r1.w, xi4, yi4), \
                 onehot_asm(r2.x, r2.y, xi4, yi4), onehot_asm(r2.z, r2.w, xi4, yi4), \
                 onehot_asm(r3.x, r3.y, xi4, yi4), onehot_asm(r3.z, r3.w, xi4, yi4), \
                 R1, R2, R4, R8, R16, R32, R64)

        float4 a0 = jp[0], a1 = jp[1], a2 = jp[2], a3 = jp[3];
        float4 b0 = jp[4], b1 = jp[5], b2 = jp[6], b3 = jp[7];
        jp += 8;
        #pragma unroll 1
        for (int it = 0; it < 7; ++it) {           // 7 x 16 + 16 = 128 pairs
            GRP8(a0, a1, a2, a3);
            a0 = jp[0]; a1 = jp[1]; a2 = jp[2]; a3 = jp[3];
            GRP8(b0, b1, b2, b3);
            b0 = jp[4]; b1 = jp[5]; b2 = jp[6]; b3 = jp[7];
            jp += 8;
        }
        GRP8(a0, a1, a2, a3);
        GRP8(b0, b1, b2, b3);
        #undef GRP8

        // flush planes -> byte-packed counts (overwrite own zeroed column)
        const u32 lo[7] = { (u32)R1,  (u32)R2,  (u32)R4,  (u32)R8,
                            (u32)R16, (u32)R32, (u32)R64 };
        const u32 hi[7] = { (u32)(R1>>32),  (u32)(R2>>32),  (u32)(R4>>32),
                            (u32)(R8>>32),  (u32)(R16>>32), (u32)(R32>>32),
                            (u32)(R64>>32) };
        #pragma unroll
        for (int w = 0; w < 9; ++w) {
            u32 acc = 0;
            #pragma unroll
            for (int L = 0; L < 7; ++L) {
                u32 nib = (w < 8) ? ((lo[L] >> (4 * w)) & 0xFu)
                                  : (hi[L] & 0xFu);
                acc += ((nib * 0x00204081u) & 0x01010101u) << L;
            }
            s_h[w * BLOCK + tid] = acc;
        }
    }
    __syncthreads();

    // ---- Phase 2: byte-wise reduce over 64 slices (72 tasks)
    if (tid < IPB * 9) {                           // 72
        const int ril = tid & (IPB - 1);
        const int w   = tid >> 3;                  // 0..8
        u32 lo = 0u, hi = 0u;
        #pragma unroll 8
        for (int sl = 0; sl < SLICES; ++sl) {
            u32 a = s_h[(w << 9) + sl * IPB + ril];
            lo += a & 0x00FF00FFu;
            hi += (a >> 8) & 0x00FF00FFu;
        }
        u32 s0 = lo & 0xFFFFu;
        u32 s1 = hi & 0xFFFFu;
        u32 s2 = lo >> 16;
        u32 s3 = hi >> 16;
        const u32 sel  = s_wsel[ril];
        const u32 base = (u32)(w * 4);
        s0 -= (sel == base + 0u);
        s1 -= (sel == base + 1u);
        s2 -= (sel == base + 2u);
        s3 -= (sel == base + 3u);
        s_rgrid[ril][base + 0] = (float)s0;
        s_rgrid[ril][base + 1] = (float)s1;
        s_rgrid[ril][base + 2] = (float)s2;
        s_rgrid[ril][base + 3] = (float)s3;
    }
    __syncthreads();

    // ---- Phase 3: fused GEMM  out[i][h] = sum_k grid[i][k]*W[h][k] + b[h]
    const int h  = tid & (HID - 1);                // 0..127
    const int r0 = tid >> 7;                       // 0..3
    const float4* W4 = (const float4*)Wg;          // [128][9] float4

    const float bh = bias[h];
    float acc0 = bh, acc1 = bh;

    #pragma unroll
    for (int k4 = 0; k4 < 9; ++k4) {
        float4 w4 = W4[h * 9 + k4];
        float4 g0 = *(const float4*)&s_rgrid[r0    ][k4 * 4];
        float4 g1 = *(const float4*)&s_rgrid[r0 + 4][k4 * 4];
        acc0 += g0.x * w4.x + g0.y * w4.y + g0.z * w4.z + g0.w * w4.w;
        acc1 += g1.x * w4.x + g1.y * w4.y + g1.z * w4.z + g1.w * w4.w;
    }

    const int obase = bid * IPB;
    out[(obase + r0    ) * HID + h] = acc0;
    out[(obase + r0 + 4) * HID + h] = acc1;
}

extern "C" void kernel_launch(void* const* d_in, const int* in_sizes, int n_in,
                              void* d_out, int out_size, void* d_ws, size_t ws_size,
                              hipStream_t stream) {
    // inputs: 0=hidden_state (unused), 1=obs1 (unused), 2=obs2, 3=W, 4=b
    const float* obs2 = (const float*)d_in[2];
    const float* W    = (const float*)d_in[3];
    const float* b    = (const float*)d_in[4];
    float* out        = (float*)d_out;
    (void)in_sizes; (void)n_in; (void)out_size; (void)d_ws; (void)ws_size;

    hipLaunchKernelGGL(pool_kernel, dim3(NB), dim3(BLOCK), 0, stream,
                       obs2, W, b, out);
}